// Round 5
// baseline (108.164 us; speedup 1.0000x reference)
//
#include <hip/hip_runtime.h>

// DRMM scoring kernel, round 5.
// Shapes: B=32, D=8, QL=16, DL=512, E=300, V=50000, 5 histogram bins.
// One block per (b,d) doc pair; 256 threads, T=2 doc tokens per lane.
// Two register pipelines, both reload-in-place (no rotation):
//   - global doc rows: depth-5 circular float4 slots (round 4, proven)
//   - NEW: q-chunk register file qr0..qr15, reloaded one chunk ahead right
//     after last use -> each ds_read_b128 gets ~250 issue-cycles of FMA cover
//     instead of stalling ~120 cyc at first use every chunk.
// Per-token dot/norm summation order is bit-identical to rounds 1-4 (passing).

constexpr int Bn  = 32;
constexpr int Dn  = 8;
constexpr int QLn = 16;
constexpr int DLn = 512;
constexpr int En  = 300;

__global__ __launch_bounds__(256) void drmm_score(
    const int*   __restrict__ bq,    // [B,QL]
    const int*   __restrict__ bd,    // [B,D,DL]
    const float* __restrict__ emb,   // [V,E]
    const float* __restrict__ w_g,   // [E]
    const float* __restrict__ b_g,   // [1]
    const float* __restrict__ w1,    // [5]
    const float* __restrict__ b1,    // [1]
    const float* __restrict__ w2,    // [1]
    const float* __restrict__ b2,    // [1]
    const float* __restrict__ w_o,   // [1]
    const float* __restrict__ b_o,   // [1]
    float*       __restrict__ out)   // [B*D]
{
    __shared__ __attribute__((aligned(16))) float q_lds[QLn * En]; // 19200 B
    __shared__ float pn_s[QLn][17];
    __shared__ float pg_s[QLn][17];
    __shared__ float qn_s[QLn];
    __shared__ float gate_s[QLn];
    __shared__ float tw_s[QLn];
    __shared__ unsigned long long hist_s[QLn]; // 5 x 12-bit packed counters per q
    __shared__ float wsum_s[QLn];

    const int n   = blockIdx.x;   // 0..255  (b*8 + d)
    const int b   = n >> 3;
    const int tid = threadIdx.x;  // 0..255

    // ---- Phase 1: stage query embeddings into LDS (float4 granularity) ----
    for (int idx = tid; idx < QLn * (En / 4); idx += 256) {   // 1200 float4s
        const int  q   = idx / (En / 4);
        const int  c   = idx - q * (En / 4);
        const long tok = bq[b * QLn + q];
        *reinterpret_cast<float4*>(&q_lds[q * En + c * 4]) =
            *reinterpret_cast<const float4*>(emb + tok * (long)En + c * 4);
    }
    if (tid < QLn) hist_s[tid] = 0ull;
    __syncthreads();

    // ---- Phase 2: query norms + gate logits (16 threads per q) ----
    {
        const int q = tid >> 4, j = tid & 15;
        float pn = 0.f, pg = 0.f;
        for (int e = j; e < En; e += 16) {
            const float v = q_lds[q * En + e];
            pn = fmaf(v, v, pn);
            pg = fmaf(v, w_g[e], pg);
        }
        pn_s[q][j] = pn;
        pg_s[q][j] = pg;
    }
    __syncthreads();
    if (tid < QLn) {
        float sn = 0.f, sg = 0.f;
        for (int j = 0; j < 16; ++j) { sn += pn_s[tid][j]; sg += pg_s[tid][j]; }
        qn_s[tid]   = sqrtf(sn);
        gate_s[tid] = sg + b_g[0];
    }
    __syncthreads();
    if (tid == 0) {
        float m = gate_s[0];
        for (int q = 1; q < QLn; ++q) m = fmaxf(m, gate_s[q]);
        float ex[QLn];
        float s = 0.f;
        for (int q = 0; q < QLn; ++q) { ex[q] = expf(gate_s[q] - m); s += ex[q]; }
        for (int q = 0; q < QLn; ++q) tw_s[q] = ex[q] / s;
    }
    __syncthreads();

    // ---- Phase 3: per-token cosine sims; 2 tokens per lane ----
    const long tok0 = bd[n * DLn + tid];
    const long tok1 = bd[n * DLn + tid + 256];
    const float* __restrict__ r0 = emb + tok0 * (long)En;
    const float* __restrict__ r1 = emb + tok1 * (long)En;

    float acc0[QLn], acc1[QLn];
#pragma unroll
    for (int q = 0; q < QLn; ++q) { acc0[q] = 0.f; acc1[q] = 0.f; }
    float nr0 = 0.f, nr1 = 0.f;

    // q-chunk register file: current chunk's 16 float4s
    float4 qr0  = *reinterpret_cast<const float4*>(&q_lds[ 0 * En]);
    float4 qr1  = *reinterpret_cast<const float4*>(&q_lds[ 1 * En]);
    float4 qr2  = *reinterpret_cast<const float4*>(&q_lds[ 2 * En]);
    float4 qr3  = *reinterpret_cast<const float4*>(&q_lds[ 3 * En]);
    float4 qr4  = *reinterpret_cast<const float4*>(&q_lds[ 4 * En]);
    float4 qr5  = *reinterpret_cast<const float4*>(&q_lds[ 5 * En]);
    float4 qr6  = *reinterpret_cast<const float4*>(&q_lds[ 6 * En]);
    float4 qr7  = *reinterpret_cast<const float4*>(&q_lds[ 7 * En]);
    float4 qr8  = *reinterpret_cast<const float4*>(&q_lds[ 8 * En]);
    float4 qr9  = *reinterpret_cast<const float4*>(&q_lds[ 9 * En]);
    float4 qr10 = *reinterpret_cast<const float4*>(&q_lds[10 * En]);
    float4 qr11 = *reinterpret_cast<const float4*>(&q_lds[11 * En]);
    float4 qr12 = *reinterpret_cast<const float4*>(&q_lds[12 * En]);
    float4 qr13 = *reinterpret_cast<const float4*>(&q_lds[13 * En]);
    float4 qr14 = *reinterpret_cast<const float4*>(&q_lds[14 * En]);
    float4 qr15 = *reinterpret_cast<const float4*>(&q_lds[15 * En]);

    // one q's 8 FMAs, then reload that q-reg from the NEXT chunk (EE+4)
#define QS_R(QI, d0, d1, EE)                                                   \
    {                                                                          \
        float s0 = acc0[QI];                                                   \
        s0 = fmaf((d0).x, qr##QI.x, s0);                                       \
        s0 = fmaf((d0).y, qr##QI.y, s0);                                       \
        s0 = fmaf((d0).z, qr##QI.z, s0);                                       \
        s0 = fmaf((d0).w, qr##QI.w, s0);                                       \
        acc0[QI] = s0;                                                         \
        float s1 = acc1[QI];                                                   \
        s1 = fmaf((d1).x, qr##QI.x, s1);                                       \
        s1 = fmaf((d1).y, qr##QI.y, s1);                                       \
        s1 = fmaf((d1).z, qr##QI.z, s1);                                       \
        s1 = fmaf((d1).w, qr##QI.w, s1);                                       \
        acc1[QI] = s1;                                                         \
        qr##QI = *reinterpret_cast<const float4*>(&q_lds[QI * En + (EE) + 4]); \
    }
#define QS_N(QI, d0, d1, EE)                                                   \
    {                                                                          \
        float s0 = acc0[QI];                                                   \
        s0 = fmaf((d0).x, qr##QI.x, s0);                                       \
        s0 = fmaf((d0).y, qr##QI.y, s0);                                       \
        s0 = fmaf((d0).z, qr##QI.z, s0);                                       \
        s0 = fmaf((d0).w, qr##QI.w, s0);                                       \
        acc0[QI] = s0;                                                         \
        float s1 = acc1[QI];                                                   \
        s1 = fmaf((d1).x, qr##QI.x, s1);                                       \
        s1 = fmaf((d1).y, qr##QI.y, s1);                                       \
        s1 = fmaf((d1).z, qr##QI.z, s1);                                       \
        s1 = fmaf((d1).w, qr##QI.w, s1);                                       \
        acc1[QI] = s1;                                                         \
    }
#define QS_ALL(OP, d0, d1, EE)                                                 \
    OP(0, d0, d1, EE)  OP(1, d0, d1, EE)  OP(2, d0, d1, EE)  OP(3, d0, d1, EE) \
    OP(4, d0, d1, EE)  OP(5, d0, d1, EE)  OP(6, d0, d1, EE)  OP(7, d0, d1, EE) \
    OP(8, d0, d1, EE)  OP(9, d0, d1, EE)  OP(10, d0, d1, EE) OP(11, d0, d1, EE)\
    OP(12, d0, d1, EE) OP(13, d0, d1, EE) OP(14, d0, d1, EE) OP(15, d0, d1, EE)

#define DRMM_NORMS(d0, d1)                                                \
    nr0 = fmaf((d0).x, (d0).x, nr0);                                      \
    nr0 = fmaf((d0).y, (d0).y, nr0);                                      \
    nr0 = fmaf((d0).z, (d0).z, nr0);                                      \
    nr0 = fmaf((d0).w, (d0).w, nr0);                                      \
    nr1 = fmaf((d1).x, (d1).x, nr1);                                      \
    nr1 = fmaf((d1).y, (d1).y, nr1);                                      \
    nr1 = fmaf((d1).z, (d1).z, nr1);                                      \
    nr1 = fmaf((d1).w, (d1).w, nr1);

    // chunk with q-reload for next chunk
#define DRMM_CHUNK_R(d0, d1, EE) { DRMM_NORMS(d0, d1) QS_ALL(QS_R, d0, d1, EE) }
    // final chunk, no q-reload
#define DRMM_CHUNK_N(d0, d1, EE) { DRMM_NORMS(d0, d1) QS_ALL(QS_N, d0, d1, EE) }

    // compute slot's chunk (with q-reload), then reload the SAME global slot
    // from 5 chunks ahead
#define DRMM_STEP_R(SA, SB, EE)                                           \
    do {                                                                  \
        DRMM_CHUNK_R(SA, SB, (EE));                                       \
        SA = *reinterpret_cast<const float4*>(r0 + (EE) + 20);            \
        SB = *reinterpret_cast<const float4*>(r1 + (EE) + 20);            \
    } while (0)

    // prologue: global slots hold chunks 0..4 (10 loads in flight)
    float4 s0a = *reinterpret_cast<const float4*>(r0 + 0);
    float4 s1a = *reinterpret_cast<const float4*>(r1 + 0);
    float4 s0b = *reinterpret_cast<const float4*>(r0 + 4);
    float4 s1b = *reinterpret_cast<const float4*>(r1 + 4);
    float4 s0c = *reinterpret_cast<const float4*>(r0 + 8);
    float4 s1c = *reinterpret_cast<const float4*>(r1 + 8);
    float4 s0d = *reinterpret_cast<const float4*>(r0 + 12);
    float4 s1d = *reinterpret_cast<const float4*>(r1 + 12);
    float4 s0e = *reinterpret_cast<const float4*>(r0 + 16);
    float4 s1e = *reinterpret_cast<const float4*>(r1 + 16);

#pragma unroll 1
    for (int k = 0; k < 14; ++k) {          // chunks 0..69, global reload 5..74
        const int e = k * 20;
        DRMM_STEP_R(s0a, s1a, e + 0);
        DRMM_STEP_R(s0b, s1b, e + 4);
        DRMM_STEP_R(s0c, s1c, e + 8);
        DRMM_STEP_R(s0d, s1d, e + 12);
        DRMM_STEP_R(s0e, s1e, e + 16);
    }
    // epilogue: chunks 70..74, q-reload continues through chunk 73
    DRMM_CHUNK_R(s0a, s1a, 280);
    DRMM_CHUNK_R(s0b, s1b, 284);
    DRMM_CHUNK_R(s0c, s1c, 288);
    DRMM_CHUNK_R(s0d, s1d, 292);
    DRMM_CHUNK_N(s0e, s1e, 296);
#undef DRMM_STEP_R
#undef DRMM_CHUNK_R
#undef DRMM_CHUNK_N
#undef DRMM_NORMS
#undef QS_ALL
#undef QS_R
#undef QS_N

    const float dn0 = sqrtf(nr0);
    const float dn1 = sqrtf(nr1);

    unsigned long long cnt[QLn];
#pragma unroll
    for (int q = 0; q < QLn; ++q) {
        unsigned long long v = 0ull;
        {
            const float denom = fmaxf(qn_s[q] * dn0, 1e-8f);
            const float c     = acc0[q] / denom;
            int bin = -1;
            if      (c >= -1.0f && c < -0.5f) bin = 0;
            else if (c >= -0.5f && c <  0.0f) bin = 1;
            else if (c >=  0.0f && c <  0.5f) bin = 2;
            else if (c >=  0.5f && c <  1.0f) bin = 3;
            else if (c ==  1.0f)              bin = 4;
            if (bin >= 0) v += 1ull << (12 * bin);
        }
        {
            const float denom = fmaxf(qn_s[q] * dn1, 1e-8f);
            const float c     = acc1[q] / denom;
            int bin = -1;
            if      (c >= -1.0f && c < -0.5f) bin = 0;
            else if (c >= -0.5f && c <  0.0f) bin = 1;
            else if (c >=  0.0f && c <  0.5f) bin = 2;
            else if (c >=  0.5f && c <  1.0f) bin = 3;
            else if (c ==  1.0f)              bin = 4;
            if (bin >= 0) v += 1ull << (12 * bin);
        }
        cnt[q] = v;
    }

    const int lane = tid & 63;
#pragma unroll
    for (int q = 0; q < QLn; ++q) {
        unsigned long long v = cnt[q];
        for (int off = 32; off > 0; off >>= 1) v += __shfl_down(v, off, 64);
        if (lane == 0) atomicAdd(&hist_s[q], v);
    }
    __syncthreads();

    // ---- Phase 4: ffnn + gated sum -> score ----
    if (tid < QLn) {
        const unsigned long long h = hist_s[tid];
        float f = 0.f;
        f = fmaf((float)((h >>  0) & 0xFFFull), w1[0], f);
        f = fmaf((float)((h >> 12) & 0xFFFull), w1[1], f);
        f = fmaf((float)((h >> 24) & 0xFFFull), w1[2], f);
        f = fmaf((float)((h >> 36) & 0xFFFull), w1[3], f);
        f = fmaf((float)((h >> 48) & 0xFFFull), w1[4], f);
        f += b1[0];
        f = f * w2[0] + b2[0];
        wsum_s[tid] = f * tw_s[tid];
    }
    __syncthreads();
    if (tid == 0) {
        float s = 0.f;
        for (int q = 0; q < QLn; ++q) s += wsum_s[q];
        out[n] = s * w_o[0] + b_o[0];
    }
}

extern "C" void kernel_launch(void* const* d_in, const int* in_sizes, int n_in,
                              void* d_out, int out_size, void* d_ws, size_t ws_size,
                              hipStream_t stream) {
    const int*   bq  = (const int*)  d_in[0];  // batch_queries
    // d_in[1] query_len: unused by reference
    const int*   bd  = (const int*)  d_in[2];  // batch_docs
    // d_in[3] doc_len: unused by reference
    const float* emb = (const float*)d_in[4];
    const float* w_g = (const float*)d_in[5];
    const float* b_g = (const float*)d_in[6];
    const float* w1  = (const float*)d_in[7];
    const float* b1  = (const float*)d_in[8];
    const float* w2  = (const float*)d_in[9];
    const float* b2  = (const float*)d_in[10];
    const float* w_o = (const float*)d_in[11];
    const float* b_o = (const float*)d_in[12];

    drmm_score<<<Bn * Dn, 256, 0, stream>>>(
        bq, bd, emb, w_g, b_g, w1, b1, w2, b2, w_o, b_o, (float*)d_out);
}